// Round 1
// baseline (304.902 us; speedup 1.0000x reference)
//
#include <hip/hip_runtime.h>

// FFTChainMatrix == block-circulant matmul.
//   y[tok, o*64+t] = sum_{i,u} Wd[o*64+t][i*64+u] * x[tok][i*64+u]
//   Wd[o*64+t][i*64+u] = (sum_m cw[m]*params[m,o,i,:])[(t-u) mod 64]
// Pipeline: (1) cast x fp32->bf16, (2) materialize Wd in bf16 (B^T layout:
// [out=4096][in=4096], K contiguous), (3) m97-style 128x128 bf16 MFMA GEMM.

typedef unsigned short u16;
typedef __attribute__((ext_vector_type(8))) short bf16x8;   // 8 bf16 (4 VGPRs)
typedef __attribute__((ext_vector_type(4))) float f32x4;

#define TOK  4096   // B*S
#define INF  4096
#define OUTF 4096

__device__ __forceinline__ u16 f2bf(float f) {   // RNE fp32 -> bf16
    union { float f; unsigned u; } v; v.f = f;
    unsigned r = v.u + 0x7FFFu + ((v.u >> 16) & 1u);
    return (u16)(r >> 16);
}

// ---- x (fp32) -> bf16, 8 elems/thread --------------------------------------
__global__ void cvt_bf16(const float* __restrict__ x, u16* __restrict__ y, int n8) {
    int i = blockIdx.x * blockDim.x + threadIdx.x;
    if (i >= n8) return;
    const float4* x4 = (const float4*)x;
    float4 a = x4[2 * i], b = x4[2 * i + 1];
    union { u16 u[8]; uint4 v; } o;
    o.u[0] = f2bf(a.x); o.u[1] = f2bf(a.y); o.u[2] = f2bf(a.z); o.u[3] = f2bf(a.w);
    o.u[4] = f2bf(b.x); o.u[5] = f2bf(b.y); o.u[6] = f2bf(b.z); o.u[7] = f2bf(b.w);
    ((uint4*)y)[i] = o.v;
}

// ---- materialize dense block-circulant W (bf16) ----------------------------
// one block per (o,i) pair; params layout (m,o,i,k): strides 262144/4096/64/1
__global__ void build_w(const float* __restrict__ p, const float* __restrict__ cw,
                        u16* __restrict__ W) {
    const int o = blockIdx.x >> 6, i = blockIdx.x & 63;
    __shared__ u16 c[64];
    const int t = threadIdx.x;
    if (t < 64) {
        const float* base = p + (size_t)o * 4096 + i * 64 + t;
        float v = cw[0] * base[0]      + cw[1] * base[262144]
                + cw[2] * base[524288] + cw[3] * base[786432];
        c[t] = f2bf(v);
    }
    __syncthreads();
    // W[(o*64+r)*4096 + i*64 + u] = c[(r-u) & 63]; ushort4 stores
    for (int e4 = t; e4 < 1024; e4 += 256) {
        int r  = e4 >> 4;
        int u0 = (e4 & 15) * 4;
        ushort4 v;
        v.x = c[(r - u0)     & 63];
        v.y = c[(r - u0 - 1) & 63];
        v.z = c[(r - u0 - 2) & 63];
        v.w = c[(r - u0 - 3) & 63];
        *(ushort4*)&W[((size_t)(o * 64 + r) << 12) + i * 64 + u0] = v;
    }
}

// ---- 128x128 bf16 MFMA GEMM, B^T operand, global_load_lds width-16 ---------
#define BM 128
#define BN 128
#define BK 32

__global__ __launch_bounds__(256) void gemm_bt(
    const u16* __restrict__ A,   // [TOK][K]  bf16 (x)
    const u16* __restrict__ Bw,  // [N][K]    bf16 (W, K contiguous)
    float* __restrict__ C) {     // [TOK][N]  fp32
    __shared__ u16 sA[BM * BK];  // 8 KiB, row-major [128][32]
    __shared__ u16 sB[BN * BK];  // 8 KiB

    const int tid  = threadIdx.x;
    const int lane = tid & 63;
    const int wid  = tid >> 6;              // 4 waves
    const int wm   = wid >> 1, wn = wid & 1;
    const int lm   = lane & 15;             // m/n within 16x16 frag
    const int kq   = (lane >> 4) * 8;       // k offset within BK=32
    const int tileM = blockIdx.y * BM;
    const int tileN = blockIdx.x * BN;
    const int K = INF, N = OUTF;

    f32x4 acc[4][4];
#pragma unroll
    for (int i = 0; i < 4; ++i)
#pragma unroll
        for (int j = 0; j < 4; ++j) acc[i][j] = (f32x4){0.f, 0.f, 0.f, 0.f};

    // staging: 2 issues x 4 waves x 64 lanes x 16B = 8 KiB per matrix per K-tile.
    // LDS dest is wave-uniform base + lane*16 -> flat [row][k] order matches.
    const int e0 = (wid * 64 + lane) * 8;         // flat bf16 elem idx, issue 0
    const int e1 = (256 * 1 + wid * 64 + lane) * 8;
    const u16* gA0 = A  + (size_t)(tileM + (e0 >> 5)) * K + (e0 & 31);
    const u16* gA1 = A  + (size_t)(tileM + (e1 >> 5)) * K + (e1 & 31);
    const u16* gB0 = Bw + (size_t)(tileN + (e0 >> 5)) * K + (e0 & 31);
    const u16* gB1 = Bw + (size_t)(tileN + (e1 >> 5)) * K + (e1 & 31);
    u16* lA0 = &sA[wid * 512];
    u16* lA1 = &sA[2048 + wid * 512];
    u16* lB0 = &sB[wid * 512];
    u16* lB1 = &sB[2048 + wid * 512];

#define GLD(g, l) __builtin_amdgcn_global_load_lds(                         \
        (const __attribute__((address_space(1))) void*)(g),                 \
        (__attribute__((address_space(3))) void*)(l), 16, 0, 0)

    for (int kt = 0; kt < K; kt += BK) {
        __syncthreads();               // previous tile's LDS reads done
        GLD(gA0 + kt, lA0);
        GLD(gA1 + kt, lA1);
        GLD(gB0 + kt, lB0);
        GLD(gB1 + kt, lB1);
        __syncthreads();               // compiler drains vmcnt(0) before barrier

        bf16x8 af[4], bf[4];
#pragma unroll
        for (int mi = 0; mi < 4; ++mi)
            af[mi] = *(const bf16x8*)&sA[(wm * 64 + mi * 16 + lm) * BK + kq];
#pragma unroll
        for (int ni = 0; ni < 4; ++ni)
            bf[ni] = *(const bf16x8*)&sB[(wn * 64 + ni * 16 + lm) * BK + kq];
#pragma unroll
        for (int mi = 0; mi < 4; ++mi)
#pragma unroll
            for (int ni = 0; ni < 4; ++ni)
                acc[mi][ni] = __builtin_amdgcn_mfma_f32_16x16x32_bf16(
                    af[mi], bf[ni], acc[mi][ni], 0, 0, 0);
    }
#undef GLD

    // epilogue: C/D layout col=lane&15, row=(lane>>4)*4+reg  [m89-verified]
    const int r0 = (lane >> 4) * 4;
#pragma unroll
    for (int mi = 0; mi < 4; ++mi) {
#pragma unroll
        for (int ni = 0; ni < 4; ++ni) {
            const int row = tileM + wm * 64 + mi * 16 + r0;
            const int col = tileN + wn * 64 + ni * 16 + lm;
            f32x4 v = acc[mi][ni];
#pragma unroll
            for (int r = 0; r < 4; ++r)
                C[(size_t)(row + r) * N + col] = v[r];
        }
    }
}

extern "C" void kernel_launch(void* const* d_in, const int* in_sizes, int n_in,
                              void* d_out, int out_size, void* d_ws, size_t ws_size,
                              hipStream_t stream) {
    const float* x      = (const float*)d_in[0];  // (2,2048,4096) fp32
    const float* params = (const float*)d_in[1];  // (4,64,64,64)  fp32
    const float* cw     = (const float*)d_in[2];  // (4,)          fp32
    float* out = (float*)d_out;                   // (2,2048,4096) fp32

    u16* Xb = (u16*)d_ws;                          // 32 MiB
    u16* Wb = Xb + (size_t)TOK * INF;              // 32 MiB

    const int n8 = TOK * INF / 8;
    cvt_bf16<<<(n8 + 255) / 256, 256, 0, stream>>>(x, Xb, n8);
    build_w<<<64 * 64, 256, 0, stream>>>(params, cw, Wb);
    dim3 grid(OUTF / BN, TOK / BM);
    gemm_bt<<<grid, 256, 0, stream>>>(Xb, Wb, out);
}

// Round 2
// 216.911 us; speedup vs baseline: 1.4057x; 1.4057x over previous
//
#include <hip/hip_runtime.h>
#include <math.h>

// FFTChainMatrix via frequency-domain factorization (31x fewer FLOPs than dense):
//   T1: XF[f][tok][2i+reim] = rfft_64(x blocks)          (MFMA GEMM K=64, N=66)
//   T2: per f: YF = XF . Bf[f], Bf = [[cr,ci],[-ci,cr]]  (MFMA GEMM K=128, N=128, in-place)
//   T3: y[tok][o*64+t] = sum_f wf/64 * (Yr cos - Yi sin) (MFMA GEMM K=66->96, N=64)
// cwf[o,i,f] = rfft(sum_m w_m params[m,o,i,:])[f]  (prep kernels)

typedef unsigned short u16;
typedef unsigned int   u32;
typedef __attribute__((ext_vector_type(8))) short bf16x8;
typedef __attribute__((ext_vector_type(4))) float f32x4;

#define TWO_PI 6.2831853071795864769f

// workspace layout (u16 element offsets)
#define XF_ELEMS (33u * 4096u * 128u)   // 17,301,504  (in-place YF after T2)
#define BF_OFF   XF_ELEMS
#define BF_ELEMS (33u * 128u * 128u)    // 540,672
#define DT_OFF   (BF_OFF + BF_ELEMS)
#define DT_ELEMS (2u * 80u * 40u)       // 6,400   Dt[kt][n=2f+reim pad80][k pad40]
#define E_OFF    (DT_OFF + DT_ELEMS)
#define E_ELEMS  (64u * 3u * 40u)       // 7,680   E[t][kt][k pad40]

__device__ __forceinline__ u16 f2bf(float f) {   // RNE fp32 -> bf16
    union { float f; unsigned u; } v; v.f = f;
    unsigned r = v.u + 0x7FFFu + ((v.u >> 16) & 1u);
    return (u16)(r >> 16);
}

// ---- constant tables: DFT (Dt) and iDFT (E), zero-padded ------------------
__global__ void prep_tables(u16* __restrict__ Dt, u16* __restrict__ E) {
    const int tid = threadIdx.x;
    // Dt[kt][n][kk]: n=2f+reim, value n even: cos(2pi f k/64), odd: -sin
    for (int e = tid; e < (int)DT_ELEMS; e += 256) {
        int kt = e / 3200, rem = e % 3200, n = rem / 40, kk = rem % 40;
        int k = kt * 32 + kk;
        float v = 0.f;
        if (n < 66 && kk < 32) {
            int f = n >> 1;
            float ang = TWO_PI * (float)((f * k) & 63) * (1.f / 64.f);
            v = (n & 1) ? -sinf(ang) : cosf(ang);
        }
        Dt[e] = f2bf(v);
    }
    // E[t][kt][kk]: k=2f+reim, value (wf/64)*(k even: cos(2pi f t/64), odd: -sin)
    for (int e = tid; e < (int)E_ELEMS; e += 256) {
        int t = e / 120, rem = e % 120, kt = rem / 40, kk = rem % 40;
        int k = kt * 32 + kk;
        float v = 0.f;
        if (k < 66 && kk < 32) {
            int f = k >> 1;
            float wf = (f == 0 || f == 32) ? 1.f : 2.f;
            float ang = TWO_PI * (float)((f * t) & 63) * (1.f / 64.f);
            v = (wf * (1.f / 64.f)) * ((k & 1) ? -sinf(ang) : cosf(ang));
        }
        E[e] = f2bf(v);
    }
}

// ---- Bf[f][n=2o+reim][k=2i+reim] from params ------------------------------
__global__ void prep_bf(const float* __restrict__ p, const float* __restrict__ cw,
                        u16* __restrict__ Bf) {
    const int o = blockIdx.x >> 6, i = blockIdx.x & 63;
    __shared__ float ct[64];
    __shared__ float w[4];
    const int t = threadIdx.x;
    if (t < 4) w[t] = cw[t];
    __syncthreads();
    {
        const float* base = p + (size_t)o * 4096 + i * 64 + t;
        ct[t] = w[0] * base[0]      + w[1] * base[262144]
              + w[2] * base[524288] + w[3] * base[786432];
    }
    __syncthreads();
    if (t < 33) {   // f = t:  cr = sum ct*cos, ci = -sum ct*sin
        float cr = 0.f, ci = 0.f;
        for (int u = 0; u < 64; ++u) {
            float ang = TWO_PI * (float)((t * u) & 63) * (1.f / 64.f);
            float s, c; sincosf(ang, &s, &c);
            cr += ct[u] * c; ci -= ct[u] * s;
        }
        u16* b = Bf + (size_t)t * 16384 + (2 * o) * 128 + 2 * i;
        b[0]   = f2bf(cr);  b[1]   = f2bf(-ci);   // row 2o:   Yr += xr*cr - xi*ci
        b[128] = f2bf(ci);  b[129] = f2bf(cr);    // row 2o+1: Yi += xr*ci + xi*cr
    }
}

// ---- T1: DFT.  rows = (tok,i) natural order; out XF[f][tok][2i+reim] ------
__global__ __launch_bounds__(256) void t1_dft(const float* __restrict__ x,
                                              const u16* __restrict__ Dt,
                                              u16* __restrict__ XF) {
    // sA[2][256][40] = 20480, sB[2][80][40] = 6400 -> 26880 u16 (53.75 KB)
    // epilogue reuses [0,20992) as C[256][82]
    __shared__ u16 smem[26880];
    const int tid = threadIdx.x;
    const int blk = blockIdx.x;
    {   // stage A: coalesced float4 loads, cvt, ds_write b64 (8B-aligned)
        const float4* xb = (const float4*)(x + (size_t)blk * 16384);
#pragma unroll
        for (int j = 0; j < 16; ++j) {
            int c = j * 256 + tid;
            float4 v = xb[c];
            int row = c >> 4, k0 = (c & 15) * 4;
            ushort4 pk;
            pk.x = f2bf(v.x); pk.y = f2bf(v.y); pk.z = f2bf(v.z); pk.w = f2bf(v.w);
            *(ushort4*)&smem[(k0 >> 5) * 10240 + row * 40 + (k0 & 31)] = pk;
        }
        const u32* src = (const u32*)Dt;           // verbatim copy (pre-padded)
        for (int e = tid; e < 3200; e += 256)
            *(u32*)&smem[20480 + 2 * e] = src[e];
    }
    __syncthreads();
    const int lane = tid & 63, wave = tid >> 6;
    const int lm = lane & 15, kq8 = (lane >> 4) * 8;
    f32x4 acc[4][5];
#pragma unroll
    for (int mi = 0; mi < 4; ++mi)
#pragma unroll
        for (int ni = 0; ni < 5; ++ni) acc[mi][ni] = (f32x4){0.f, 0.f, 0.f, 0.f};
#pragma unroll
    for (int kt = 0; kt < 2; ++kt) {
        bf16x8 af[4], bfr[5];
#pragma unroll
        for (int mi = 0; mi < 4; ++mi)
            af[mi] = *(const bf16x8*)&smem[kt * 10240 + (wave * 64 + mi * 16 + lm) * 40 + kq8];
#pragma unroll
        for (int ni = 0; ni < 5; ++ni)
            bfr[ni] = *(const bf16x8*)&smem[20480 + kt * 3200 + (ni * 16 + lm) * 40 + kq8];
#pragma unroll
        for (int mi = 0; mi < 4; ++mi)
#pragma unroll
            for (int ni = 0; ni < 5; ++ni)
                acc[mi][ni] = __builtin_amdgcn_mfma_f32_16x16x32_bf16(
                    af[mi], bfr[ni], acc[mi][ni], 0, 0, 0);
    }
    __syncthreads();
    // epilogue 1: C -> LDS [256][82] bf16 (cols >= 66 dropped)
    const int r0 = (lane >> 4) * 4;
#pragma unroll
    for (int mi = 0; mi < 4; ++mi)
#pragma unroll
        for (int ni = 0; ni < 5; ++ni) {
            int col = ni * 16 + lm;
            if (col < 66) {
                int row = wave * 64 + mi * 16 + r0;
                f32x4 v = acc[mi][ni];
#pragma unroll
                for (int r = 0; r < 4; ++r) smem[(row + r) * 82 + col] = f2bf(v[r]);
            }
        }
    __syncthreads();
    // epilogue 2: per (f, tok_local) segment: 64 (re,im) dwords -> 256 B contiguous
    if (tid < 132) {
        int f = tid >> 2, tokl = tid & 3;
        u32* dst = (u32*)XF + (size_t)f * 262144 + (size_t)(blk * 4 + tokl) * 64;
#pragma unroll
        for (int jb = 0; jb < 16; ++jb) {
            uint4 tmp;
            u32* q = (u32*)&tmp;
#pragma unroll
            for (int jj = 0; jj < 4; ++jj) {
                int i = jb * 4 + jj;
                q[jj] = *(const u32*)&smem[(tokl * 64 + i) * 82 + 2 * f];
            }
            ((uint4*)dst)[jb] = tmp;
        }
    }
}

// ---- T2: per-frequency complex contraction (in-place on XF) ----------------
__global__ __launch_bounds__(256) void t2_freq(u16* __restrict__ XF,
                                               const u16* __restrict__ Bf) {
    __shared__ u16 sA[128 * 32];
    __shared__ u16 sB[128 * 32];
    const int f = blockIdx.y;
    u16* XFf = XF + (size_t)f * 524288;
    const u16* Bff = Bf + (size_t)f * 16384;
    const int tid = threadIdx.x, lane = tid & 63, wid = tid >> 6;
    const int wm = wid >> 1, wn = wid & 1;
    const int lm = lane & 15, kq = (lane >> 4) * 8;
    const int tileM = blockIdx.x * 128;

    f32x4 acc[4][4];
#pragma unroll
    for (int i = 0; i < 4; ++i)
#pragma unroll
        for (int j = 0; j < 4; ++j) acc[i][j] = (f32x4){0.f, 0.f, 0.f, 0.f};

    const int e0 = (wid * 64 + lane) * 8;
    const int e1 = 2048 + e0;
    const u16* gA0 = XFf + (size_t)(tileM + (e0 >> 5)) * 128 + (e0 & 31);
    const u16* gA1 = XFf + (size_t)(tileM + (e1 >> 5)) * 128 + (e1 & 31);
    const u16* gB0 = Bff + (size_t)(e0 >> 5) * 128 + (e0 & 31);
    const u16* gB1 = Bff + (size_t)(e1 >> 5) * 128 + (e1 & 31);
    u16* lA0 = &sA[wid * 512];
    u16* lA1 = &sA[2048 + wid * 512];
    u16* lB0 = &sB[wid * 512];
    u16* lB1 = &sB[2048 + wid * 512];

#define GLD(g, l) __builtin_amdgcn_global_load_lds(                         \
        (const __attribute__((address_space(1))) void*)(g),                 \
        (__attribute__((address_space(3))) void*)(l), 16, 0, 0)

#pragma unroll
    for (int kt = 0; kt < 128; kt += 32) {
        __syncthreads();
        GLD(gA0 + kt, lA0);
        GLD(gA1 + kt, lA1);
        GLD(gB0 + kt, lB0);
        GLD(gB1 + kt, lB1);
        __syncthreads();
        bf16x8 af[4], bfr[4];
#pragma unroll
        for (int mi = 0; mi < 4; ++mi)
            af[mi] = *(const bf16x8*)&sA[(wm * 64 + mi * 16 + lm) * 32 + kq];
#pragma unroll
        for (int ni = 0; ni < 4; ++ni)
            bfr[ni] = *(const bf16x8*)&sB[(wn * 64 + ni * 16 + lm) * 32 + kq];
#pragma unroll
        for (int mi = 0; mi < 4; ++mi)
#pragma unroll
            for (int ni = 0; ni < 4; ++ni)
                acc[mi][ni] = __builtin_amdgcn_mfma_f32_16x16x32_bf16(
                    af[mi], bfr[ni], acc[mi][ni], 0, 0, 0);
    }
#undef GLD

    // epilogue: bf16, in-place (all A reads completed above; rows owned by this block)
    const int r0 = (lane >> 4) * 4;
#pragma unroll
    for (int mi = 0; mi < 4; ++mi)
#pragma unroll
        for (int ni = 0; ni < 4; ++ni) {
            const int row = tileM + wm * 64 + mi * 16 + r0;
            const int col = wn * 64 + ni * 16 + lm;
            f32x4 v = acc[mi][ni];
#pragma unroll
            for (int r = 0; r < 4; ++r)
                XFf[(size_t)(row + r) * 128 + col] = f2bf(v[r]);
        }
}

// ---- T3: iDFT.  rows = (tok,o); y[tok][o*64+t] directly --------------------
__global__ __launch_bounds__(256) void t3_idft(const u16* __restrict__ YF,
                                               const u16* __restrict__ E,
                                               float* __restrict__ y) {
    __shared__ u16 sA[3 * 128 * 40];   // 15360 u16, rows padded to 40 (16B-aligned)
    __shared__ u16 sE[64 * 120];       // 7680 u16
    const int tid = threadIdx.x, lane = tid & 63, wave = tid >> 6;
    // zero sA (pads + unwritten high-k must be 0)
    for (int e = tid; e < 7680; e += 256) ((u32*)sA)[e] = 0u;
    {   // stage E verbatim (pre-padded)
        const u32* src = (const u32*)E;
        for (int e = tid; e < 3840; e += 256) ((u32*)sE)[e] = src[e];
    }
    __syncthreads();
    // gather A: 66 coalesced 256B segments (f, tok_local) -> k-major LDS rows
    const int tok0 = blockIdx.x * 2;
    for (int s = wave; s < 66; s += 4) {
        int f = s >> 1, tokl = s & 1;
        u32 v = *((const u32*)YF + (size_t)f * 262144 + (size_t)(tok0 + tokl) * 64 + lane);
        int k = 2 * f, kt = k >> 5, kk = k & 31;     // lane = o
        *(u32*)&sA[kt * 5120 + (tokl * 64 + lane) * 40 + kk] = v;
    }
    __syncthreads();
    const int lm = lane & 15, kq8 = (lane >> 4) * 8;
    f32x4 acc[2][4];
#pragma unroll
    for (int mi = 0; mi < 2; ++mi)
#pragma unroll
        for (int ni = 0; ni < 4; ++ni) acc[mi][ni] = (f32x4){0.f, 0.f, 0.f, 0.f};
#pragma unroll
    for (int kt = 0; kt < 3; ++kt) {
        bf16x8 af[2], bfr[4];
#pragma unroll
        for (int mi = 0; mi < 2; ++mi)
            af[mi] = *(const bf16x8*)&sA[kt * 5120 + (wave * 32 + mi * 16 + lm) * 40 + kq8];
#pragma unroll
        for (int ni = 0; ni < 4; ++ni)
            bfr[ni] = *(const bf16x8*)&sE[(ni * 16 + lm) * 120 + kt * 40 + kq8];
#pragma unroll
        for (int mi = 0; mi < 2; ++mi)
#pragma unroll
            for (int ni = 0; ni < 4; ++ni)
                acc[mi][ni] = __builtin_amdgcn_mfma_f32_16x16x32_bf16(
                    af[mi], bfr[ni], acc[mi][ni], 0, 0, 0);
    }
    const int r0 = (lane >> 4) * 4;
#pragma unroll
    for (int mi = 0; mi < 2; ++mi)
#pragma unroll
        for (int ni = 0; ni < 4; ++ni) {
            int row = blockIdx.x * 128 + wave * 32 + mi * 16 + r0;
            int t = ni * 16 + lm;
            f32x4 v = acc[mi][ni];
#pragma unroll
            for (int r = 0; r < 4; ++r)
                y[(size_t)(row + r) * 64 + t] = v[r];
        }
}

extern "C" void kernel_launch(void* const* d_in, const int* in_sizes, int n_in,
                              void* d_out, int out_size, void* d_ws, size_t ws_size,
                              hipStream_t stream) {
    const float* x      = (const float*)d_in[0];  // (2,2048,4096) fp32
    const float* params = (const float*)d_in[1];  // (4,64,64,64)  fp32
    const float* cw     = (const float*)d_in[2];  // (4,)          fp32
    float* out = (float*)d_out;

    u16* XF = (u16*)d_ws;
    u16* Bf = XF + BF_OFF;
    u16* Dt = XF + DT_OFF;
    u16* Eg = XF + E_OFF;

    prep_tables<<<1, 256, 0, stream>>>(Dt, Eg);
    prep_bf<<<64 * 64, 64, 0, stream>>>(params, cw, Bf);
    t1_dft<<<1024, 256, 0, stream>>>(x, Dt, XF);
    t2_freq<<<dim3(32, 33), 256, 0, stream>>>(XF, Bf);
    t3_idft<<<2048, 256, 0, stream>>>(XF, Eg, out);
}

// Round 3
// 171.532 us; speedup vs baseline: 1.7775x; 1.2646x over previous
//
#include <hip/hip_runtime.h>
#include <math.h>

// FFTChainMatrix via frequency-domain factorization (31x fewer FLOPs than dense):
//   T1: XF[f][tok][i-u32(re,im)] = rfft_64(x blocks)     (MFMA, K=64, N=66, no staging)
//   T2: per f: YF = XF . Bf[f], Bf = [[cr,ci],[-ci,cr]]  (MFMA GEMM K=128, N=128, in-place)
//   T3: y[tok][o*64+t] = sum_f wf/64 * Re(e^{iwft} YF)   (MFMA GEMM K=66->96, N=64)

typedef unsigned short u16;
typedef unsigned int   u32;
typedef __attribute__((ext_vector_type(8))) short bf16x8;
typedef __attribute__((ext_vector_type(4))) float f32x4;

#define TWO_PI 6.2831853071795864769f
#define SLICE 262144u                    // XF per-f slice, u32 elems (4096 tok * 64 i)

// workspace layout (u16 element offsets)
#define XF_ELEMS (33u * 2u * SLICE)      // 17,301,504 u16
#define BF_OFF   XF_ELEMS
#define BF_ELEMS (33u * 128u * 128u)
#define DT_OFF   (BF_OFF + BF_ELEMS)
#define DT_ELEMS (2u * 80u * 40u)        // Dt[kt][n=2f+reim pad80][k pad40]
#define E_OFF    (DT_OFF + DT_ELEMS)
#define E_ELEMS  (64u * 3u * 40u)        // E[t][kt][k pad40]

__device__ __forceinline__ u16 f2bf(float f) {   // RNE fp32 -> bf16
    union { float f; unsigned u; } v; v.f = f;
    unsigned r = v.u + 0x7FFFu + ((v.u >> 16) & 1u);
    return (u16)(r >> 16);
}

// ---- merged prep: block 0 -> Dt/E tables; blocks 1..1024 -> Bf -------------
__global__ void prep(const float* __restrict__ p, const float* __restrict__ cw,
                     u16* __restrict__ Bf, u16* __restrict__ Dt, u16* __restrict__ E) {
    const int tid = threadIdx.x;
    if (blockIdx.x == 0) {
        for (int e = tid; e < (int)DT_ELEMS; e += 256) {
            int kt = e / 3200, rem = e % 3200, n = rem / 40, kk = rem % 40;
            int k = kt * 32 + kk;
            float v = 0.f;
            if (n < 66 && kk < 32) {
                int f = n >> 1;
                float ang = TWO_PI * (float)((f * k) & 63) * (1.f / 64.f);
                v = (n & 1) ? -sinf(ang) : cosf(ang);
            }
            Dt[e] = f2bf(v);
        }
        for (int e = tid; e < (int)E_ELEMS; e += 256) {
            int t = e / 120, rem = e % 120, kt = rem / 40, kk = rem % 40;
            int k = kt * 32 + kk;
            float v = 0.f;
            if (k < 66 && kk < 32) {
                int f = k >> 1;
                float wf = (f == 0 || f == 32) ? 1.f : 2.f;
                float ang = TWO_PI * (float)((f * t) & 63) * (1.f / 64.f);
                v = (wf * (1.f / 64.f)) * ((k & 1) ? -sinf(ang) : cosf(ang));
            }
            E[e] = f2bf(v);
        }
        return;
    }
    // Bf: 4 (o,i) pairs per block
    __shared__ float  ct[4][64];
    __shared__ float2 trig[64];
    const int pr = tid >> 6, ln = tid & 63;
    if (tid < 64) {
        float s, c;
        sincosf(TWO_PI * (float)tid * (1.f / 64.f), &s, &c);
        trig[tid] = make_float2(s, c);
    }
    const int pg = (blockIdx.x - 1) * 4 + pr;     // 0..4095
    const int o = pg >> 6, i = pg & 63;
    {
        const float* base = p + (size_t)o * 4096 + i * 64 + ln;
        ct[pr][ln] = cw[0] * base[0]      + cw[1] * base[262144]
                   + cw[2] * base[524288] + cw[3] * base[786432];
    }
    __syncthreads();
    if (ln < 33) {        // f = ln
        float cr = 0.f, ci = 0.f;
        for (int u = 0; u < 64; ++u) {
            float2 sc = trig[(ln * u) & 63];
            cr += ct[pr][u] * sc.y; ci -= ct[pr][u] * sc.x;
        }
        u16* b = Bf + (size_t)ln * 16384 + (2 * o) * 128 + 2 * i;
        b[0]   = f2bf(cr);  b[1]   = f2bf(-ci);
        b[128] = f2bf(ci);  b[129] = f2bf(cr);
    }
}

// ---- T1: DFT, frags direct from global, transposed-LDS epilogue ------------
__global__ __launch_bounds__(256) void t1_dft(const float* __restrict__ x,
                                              const u16* __restrict__ Dt,
                                              u16* __restrict__ XF) {
    __shared__ u32 TR[33 * 4 * 68];   // [f][tokl][68-dword pad] = 35,904 B
    const int tid = threadIdx.x, lane = tid & 63, wave = tid >> 6;
    const int lm = lane & 15, kq8 = (lane >> 4) * 8;
    const int blk = blockIdx.x;
    const float* xb = x + (size_t)blk * 16384;

    f32x4 acc[4][5];
#pragma unroll
    for (int mi = 0; mi < 4; ++mi)
#pragma unroll
        for (int ni = 0; ni < 5; ++ni) acc[mi][ni] = (f32x4){0.f, 0.f, 0.f, 0.f};

#pragma unroll
    for (int kt = 0; kt < 2; ++kt) {
        bf16x8 bfr[5];
#pragma unroll
        for (int ni = 0; ni < 5; ++ni)   // Dt is L2-resident, 16B-aligned rows
            bfr[ni] = *(const bf16x8*)&Dt[(kt * 80 + ni * 16 + lm) * 40 + kq8];
#pragma unroll
        for (int mi = 0; mi < 4; ++mi) {
            const int row = wave * 64 + mi * 16 + lm;     // (tokl,i)
            const float* rp = xb + row * 64 + kt * 32 + kq8;
            float4 p0 = *(const float4*)rp;
            float4 p1 = *(const float4*)(rp + 4);
            union { u16 u[8]; bf16x8 v; } pk;
            pk.u[0] = f2bf(p0.x); pk.u[1] = f2bf(p0.y);
            pk.u[2] = f2bf(p0.z); pk.u[3] = f2bf(p0.w);
            pk.u[4] = f2bf(p1.x); pk.u[5] = f2bf(p1.y);
            pk.u[6] = f2bf(p1.z); pk.u[7] = f2bf(p1.w);
#pragma unroll
            for (int ni = 0; ni < 5; ++ni)
                acc[mi][ni] = __builtin_amdgcn_mfma_f32_16x16x32_bf16(
                    pk.v, bfr[ni], acc[mi][ni], 0, 0, 0);
        }
    }

    // epilogue 1: write C transposed into TR[f][tokl][i-dword], bf16 halves
    const int r0 = (lane >> 4) * 4;
#pragma unroll
    for (int mi = 0; mi < 4; ++mi)
#pragma unroll
        for (int ni = 0; ni < 5; ++ni) {
            const int col = ni * 16 + lm;
            if (col < 66) {
                const int f = col >> 1, par = col & 1;
                const int rowb = wave * 64 + mi * 16 + r0;
                f32x4 v = acc[mi][ni];
#pragma unroll
                for (int r = 0; r < 4; ++r) {
                    int rr = rowb + r, tokl = rr >> 6, ii = rr & 63;
                    ((u16*)TR)[(f * 272 + tokl * 68 + ii) * 2 + par] = f2bf(v[r]);
                }
            }
        }
    __syncthreads();
    // epilogue 2: 132 segs of 256 B; 16 segs/round (4 per wave), lanes contiguous
    u32* XFu = (u32*)XF;
#pragma unroll
    for (int rnd = 0; rnd < 9; ++rnd) {
        int s = rnd * 16 + wave * 4 + (lane >> 4);
        if (s < 132) {
            int f = s >> 2, tokl = s & 3, c = lm * 4;
            uint4 v = *(const uint4*)&TR[f * 272 + tokl * 68 + c];
            *(uint4*)&XFu[(size_t)f * SLICE + (size_t)(blk * 4 + tokl) * 64 + c] = v;
        }
    }
}

// ---- T2: per-frequency complex contraction (in-place on XF) ----------------
#define GLD(g, l) __builtin_amdgcn_global_load_lds(                         \
        (const __attribute__((address_space(1))) void*)(g),                 \
        (__attribute__((address_space(3))) void*)(l), 16, 0, 0)

__global__ __launch_bounds__(256) void t2_freq(u16* __restrict__ XF,
                                               const u16* __restrict__ Bf) {
    __shared__ u16 sA[128 * 32];
    __shared__ u16 sB[128 * 32];
    const int f = blockIdx.y;
    u16* XFf = XF + (size_t)f * (2u * SLICE);
    const u16* Bff = Bf + (size_t)f * 16384;
    const int tid = threadIdx.x, lane = tid & 63, wid = tid >> 6;
    const int wm = wid >> 1, wn = wid & 1;
    const int lm = lane & 15, kq = (lane >> 4) * 8;
    const int tileM = blockIdx.x * 128;

    f32x4 acc[4][4];
#pragma unroll
    for (int i = 0; i < 4; ++i)
#pragma unroll
        for (int j = 0; j < 4; ++j) acc[i][j] = (f32x4){0.f, 0.f, 0.f, 0.f};

    const int e0 = tid * 8, e1 = 2048 + tid * 8;
    const u16* gA0 = XFf + (size_t)(tileM + (e0 >> 5)) * 128 + (e0 & 31);
    const u16* gA1 = XFf + (size_t)(tileM + (e1 >> 5)) * 128 + (e1 & 31);
    const u16* gB0 = Bff + (size_t)(e0 >> 5) * 128 + (e0 & 31);
    const u16* gB1 = Bff + (size_t)(e1 >> 5) * 128 + (e1 & 31);
    u16* lA0 = &sA[wid * 512];
    u16* lA1 = &sA[2048 + wid * 512];
    u16* lB0 = &sB[wid * 512];
    u16* lB1 = &sB[2048 + wid * 512];

#pragma unroll
    for (int kt = 0; kt < 128; kt += 32) {
        __syncthreads();
        GLD(gA0 + kt, lA0);
        GLD(gA1 + kt, lA1);
        GLD(gB0 + kt, lB0);
        GLD(gB1 + kt, lB1);
        __syncthreads();
        bf16x8 af[4], bfr[4];
#pragma unroll
        for (int mi = 0; mi < 4; ++mi)
            af[mi] = *(const bf16x8*)&sA[(wm * 64 + mi * 16 + lm) * 32 + kq];
#pragma unroll
        for (int ni = 0; ni < 4; ++ni)
            bfr[ni] = *(const bf16x8*)&sB[(wn * 64 + ni * 16 + lm) * 32 + kq];
#pragma unroll
        for (int mi = 0; mi < 4; ++mi)
#pragma unroll
            for (int ni = 0; ni < 4; ++ni)
                acc[mi][ni] = __builtin_amdgcn_mfma_f32_16x16x32_bf16(
                    af[mi], bfr[ni], acc[mi][ni], 0, 0, 0);
    }

    const int r0 = (lane >> 4) * 4;
#pragma unroll
    for (int mi = 0; mi < 4; ++mi)
#pragma unroll
        for (int ni = 0; ni < 4; ++ni) {
            const int row = tileM + wm * 64 + mi * 16 + r0;
            const int col = wn * 64 + ni * 16 + lm;
            f32x4 v = acc[mi][ni];
#pragma unroll
            for (int r = 0; r < 4; ++r)
                XFf[(size_t)(row + r) * 128 + col] = f2bf(v[r]);
        }
}

// ---- T3: iDFT, flat unrolled gather, smart zero ----------------------------
__global__ __launch_bounds__(256) void t3_idft(const u16* __restrict__ YF,
                                               const u16* __restrict__ E,
                                               float* __restrict__ y) {
    __shared__ u16 sA[3 * 128 * 40];   // rows padded to 40 (16B-aligned)
    __shared__ u16 sE[64 * 120];
    const int tid = threadIdx.x, lane = tid & 63, wave = tid >> 6;
    u32* sA32 = (u32*)sA;
    // zero only: kt0/1 row pads (1024 u32) + all of kt2 (2560 u32)
#pragma unroll
    for (int j = 0; j < 4; ++j) {
        int e = j * 256 + tid;                      // < 1024
        int kt = e >> 9, row = (e >> 2) & 127, w = e & 3;
        sA32[kt * 2560 + row * 20 + 8 + w] = 0u;
    }
#pragma unroll
    for (int j = 0; j < 10; ++j)
        sA32[5120 + j * 256 + tid] = 0u;
    {
        const u32* src = (const u32*)E;
#pragma unroll
        for (int j = 0; j < 15; ++j)
            ((u32*)sE)[j * 256 + tid] = src[j * 256 + tid];
    }
    __syncthreads();
    // gather: 66 segs x 64 lanes = 4224 u32, thread-strided, fully unrolled
    const int tok0 = blockIdx.x * 2;
    const u32* YFu = (const u32*)YF;
#pragma unroll
    for (int j = 0; j < 17; ++j) {
        int e = j * 256 + tid;
        if (e < 4224) {
            int seg = e >> 6, o = e & 63;
            int f = seg >> 1, tokl = seg & 1;
            u32 v = YFu[(size_t)f * SLICE + (size_t)(tok0 + tokl) * 64 + o];
            int k = 2 * f;
            *(u32*)&sA[(k >> 5) * 5120 + (tokl * 64 + o) * 40 + (k & 31)] = v;
        }
    }
    __syncthreads();
    const int lm = lane & 15, kq8 = (lane >> 4) * 8;
    f32x4 acc[2][4];
#pragma unroll
    for (int mi = 0; mi < 2; ++mi)
#pragma unroll
        for (int ni = 0; ni < 4; ++ni) acc[mi][ni] = (f32x4){0.f, 0.f, 0.f, 0.f};
#pragma unroll
    for (int kt = 0; kt < 3; ++kt) {
        bf16x8 af[2], bfr[4];
#pragma unroll
        for (int mi = 0; mi < 2; ++mi)
            af[mi] = *(const bf16x8*)&sA[kt * 5120 + (wave * 32 + mi * 16 + lm) * 40 + kq8];
#pragma unroll
        for (int ni = 0; ni < 4; ++ni)
            bfr[ni] = *(const bf16x8*)&sE[(ni * 16 + lm) * 120 + kt * 40 + kq8];
#pragma unroll
        for (int mi = 0; mi < 2; ++mi)
#pragma unroll
            for (int ni = 0; ni < 4; ++ni)
                acc[mi][ni] = __builtin_amdgcn_mfma_f32_16x16x32_bf16(
                    af[mi], bfr[ni], acc[mi][ni], 0, 0, 0);
    }
    const int r0 = (lane >> 4) * 4;
#pragma unroll
    for (int mi = 0; mi < 2; ++mi)
#pragma unroll
        for (int ni = 0; ni < 4; ++ni) {
            int row = blockIdx.x * 128 + wave * 32 + mi * 16 + r0;
            int t = ni * 16 + lm;
            f32x4 v = acc[mi][ni];
#pragma unroll
            for (int r = 0; r < 4; ++r)
                y[(size_t)(row + r) * 64 + t] = v[r];
        }
}

extern "C" void kernel_launch(void* const* d_in, const int* in_sizes, int n_in,
                              void* d_out, int out_size, void* d_ws, size_t ws_size,
                              hipStream_t stream) {
    const float* x      = (const float*)d_in[0];  // (2,2048,4096) fp32
    const float* params = (const float*)d_in[1];  // (4,64,64,64)  fp32
    const float* cw     = (const float*)d_in[2];  // (4,)          fp32
    float* out = (float*)d_out;

    u16* XF = (u16*)d_ws;
    u16* Bf = XF + BF_OFF;
    u16* Dt = XF + DT_OFF;
    u16* Eg = XF + E_OFF;

    prep<<<1025, 256, 0, stream>>>(params, cw, Bf, Dt, Eg);
    t1_dft<<<1024, 256, 0, stream>>>(x, Dt, XF);
    t2_freq<<<dim3(32, 33), 256, 0, stream>>>(XF, Bf);
    t3_idft<<<2048, 256, 0, stream>>>(XF, Eg, out);
}